// Round 11
// baseline (246.063 us; speedup 1.0000x reference)
//
#include <hip/hip_runtime.h>
#include <stdint.h>

#define HIDDEN 1024
#define HEADS 16
#define HEAD_DIM 64
#define BATCH 4
#define SEQ 2048
#define NTOK (BATCH * SEQ)   // 8192

typedef __attribute__((ext_vector_type(8))) short bf16x8;
typedef __attribute__((ext_vector_type(4))) float floatx4;
typedef __attribute__((ext_vector_type(16))) float floatx16;

// log2(e) / sqrt(HEAD_DIM) : folded into Q so p = exp2(s) directly
#define SCALE_Q 0.18033688011112042f

__device__ __forceinline__ unsigned short f2bf(float f) {
    union { float f; unsigned u; } x; x.f = f;
    unsigned r = x.u + 0x7fffu + ((x.u >> 16) & 1u);
    return (unsigned short)(r >> 16);
}

__device__ __forceinline__ float fast_exp2(float x) {
#if __has_builtin(__builtin_amdgcn_exp2f)
    return __builtin_amdgcn_exp2f(x);
#else
    return exp2f(x);
#endif
}

typedef __attribute__((address_space(3))) unsigned int lds_u32;
typedef const __attribute__((address_space(1))) unsigned int gl_u32;

// async global->LDS, 16B per lane; l is the WAVE-UNIFORM base (HW scatters
// lane i's 16B to l + i*16).
__device__ __forceinline__ void async_cp16(const void* g, void* l) {
#if __has_builtin(__builtin_amdgcn_global_load_lds)
    __builtin_amdgcn_global_load_lds((gl_u32*)g, (lds_u32*)l, 16, 0, 0);
#else
    *(uint4*)((char*)l + (threadIdx.x & 63) * 16) = *(const uint4*)g;
#endif
}

// ---- fused fp32->bf16 conversion for x, Wq, Wk, Wv + zero of accp ----------
__global__ __launch_bounds__(256) void conv_all(
    const float* __restrict__ x, const float* __restrict__ Wq,
    const float* __restrict__ Wk, const float* __restrict__ Wv,
    unsigned short* __restrict__ x_bf, unsigned short* __restrict__ wq_bf,
    unsigned short* __restrict__ wk_bf, unsigned short* __restrict__ wv_bf,
    float* __restrict__ accp) {
    const int blk = blockIdx.x, tid = threadIdx.x;
    const float* src;
    unsigned short* dst;
    size_t i;
    if (blk < 8192) {
        src = x; dst = x_bf; i = (size_t)blk * 256 + tid;
        if (blk < 16) accp[blk * 256 + tid] = 0.0f;
    } else {
        int r = blk - 8192;
        int s = r >> 10;
        src = (s == 0) ? Wq : (s == 1) ? Wk : Wv;
        dst = (s == 0) ? wq_bf : (s == 1) ? wk_bf : wv_bf;
        i = (size_t)(r & 1023) * 256 + tid;
    }
    float4 v = *(const float4*)(src + 4 * i);
    unsigned short o[4];
    o[0] = f2bf(v.x); o[1] = f2bf(v.y); o[2] = f2bf(v.z); o[3] = f2bf(v.w);
    *(ushort4*)(dst + 4 * i) = *(ushort4*)o;
}

// ---- QKV GEMM: phase-interleaved schedule (T2+T3+T4+T5 port) ---------------
// Tile 256x128, BK=64, 8 waves (512 thr), wave tile 64x64 (4M x 2N wave grid).
// grid 768 = 24 nzb x 32 mb = 3 clean rounds of 256 CUs (XCD = id%8 const per
// mb -> same-X-panel blocks co-XCD). LDS: 3 bufs x (A 32K | B 16K) = 144 KB
// dynamic -> depth-2 prefetch, counted vmcnt(6) in-loop (NEVER 0 until tail).
// Per K-tile (16 total), 2 phases, each: {ds_read subtile || issue 3
// global_load_lds || lgkmcnt(0) || setprio(1) 16xMFMA setprio(0) || barrier}.
// 8-chunk XOR swizzle: LDS chunk j of row r holds global chunk j^(r&7), rows
// are 128B -> frag reads spread 16 rows over 8 chunk-groups = 2-way max
// (free, m136). Swizzle applied BOTH sides: pre-swizzled global source +
// swizzled ds_read address.
// Rationale: 4 prior 2-phase variants all pinned at 660 TF / 26% MfmaUtil =
// the documented 2-phase stage+barrier ceiling (m233/m248); the fine
// per-phase interleave is the proven escape (m196/m218: +28-73%).
// Epilogue: two 128-row transpose passes via tbuf (aliases buf 0).
// z==0 (Q): scaled by SCALE_Q.  z==2 (V): transposed output Vt[bh*64+d][t]
// with key-granule PERMUTATION (swap bits 2,3 of local token idx) so attn's
// PV B-frag is one b128.
__global__ __launch_bounds__(512, 2) void qkv_gemm(
    const unsigned short* __restrict__ X,
    const unsigned short* __restrict__ W0, const unsigned short* __restrict__ W1,
    const unsigned short* __restrict__ W2,
    const float* __restrict__ b0, const float* __restrict__ b1,
    const float* __restrict__ b2,
    unsigned short* __restrict__ O0, unsigned short* __restrict__ O1,
    unsigned short* __restrict__ O2) {
    extern __shared__ __align__(16) char smem[];   // 3 x 49152
    unsigned short* tbuf = (unsigned short*)smem;  // epilogue aliases buf 0

    const int id = blockIdx.x;
    const int mb = id & 31, nzb = id >> 5;
    const int z = nzb >> 3, nz = nzb & 7;
    const int m0 = mb * 256;
    const unsigned short* W = (z == 0) ? W0 : (z == 1) ? W1 : W2;
    const float* bias       = (z == 0) ? b0 : (z == 1) ? b1 : b2;

    const int tid = threadIdx.x, lane = tid & 63, wave = tid >> 6;  // 0..7
    const int wm = (wave >> 1) * 64;          // 0,64,128,192
    const int wn = (wave & 1) * 64;           // 0,64
    const int l15 = lane & 15, l7 = lane & 7, kq = lane >> 4;

    // staging: global col chunk = (lane&7) ^ (lane>>3)  (row&7 == lane>>3)
    const int sxc = ((lane & 7) ^ (lane >> 3)) * 8;   // shorts
    const unsigned short* ga[4];
    const unsigned short* gb[2];
#pragma unroll
    for (int j = 0; j < 4; ++j)
        ga[j] = X + (size_t)(m0 + wave * 32 + j * 8 + (lane >> 3)) * HIDDEN + sxc;
#pragma unroll
    for (int j = 0; j < 2; ++j)
        gb[j] = W + (size_t)(nz * 128 + wave * 16 + j * 8 + (lane >> 3)) * HIDDEN + sxc;

    floatx4 acc[4][4];
#pragma unroll
    for (int tm = 0; tm < 4; ++tm)
#pragma unroll
        for (int tn = 0; tn < 4; ++tn)
#pragma unroll
            for (int r = 0; r < 4; ++r) acc[tm][tn][r] = 0.f;

    auto STAGE_P0 = [&](int s) {
        char* base = smem + s * 49152;
        async_cp16(ga[0], base + (wave * 32 + 0) * 128);
        async_cp16(ga[1], base + (wave * 32 + 8) * 128);
        async_cp16(gb[0], base + 32768 + (wave * 16 + 0) * 128);
    };
    auto STAGE_P1 = [&](int s) {   // also advances pointers by one K-tile
        char* base = smem + s * 49152;
        async_cp16(ga[2], base + (wave * 32 + 16) * 128);
        async_cp16(ga[3], base + (wave * 32 + 24) * 128);
        async_cp16(gb[1], base + 32768 + (wave * 16 + 8) * 128);
#pragma unroll
        for (int j = 0; j < 4; ++j) ga[j] += 64;
        gb[0] += 64; gb[1] += 64;
    };

    // prologue: tiles 0,1 into bufs 0,1 (12 loads in flight, no wait)
    STAGE_P0(0); STAGE_P1(0);
    STAGE_P0(1); STAGE_P1(1);

    for (int kt = 0; kt < 16; ++kt) {
        const int c = kt % 3;              // compute buf
        const int bs = (kt + 2) % 3;       // stage buf (tile kt+2)
        // tile kt landed (6 newer loads stay in flight across the barrier)
        if (kt < 15) { asm volatile("s_waitcnt vmcnt(6)" ::: "memory"); }
        else         { asm volatile("s_waitcnt vmcnt(0)" ::: "memory"); }
        __builtin_amdgcn_sched_barrier(0);
        asm volatile("s_barrier" ::: "memory");
        __builtin_amdgcn_sched_barrier(0);

        const char* Ab = smem + c * 49152;
        const char* Bb = Ab + 32768;
        bf16x8 af[4][2], bf[2][2];
        // ---- phase 0: read all A frags + B tn=0,1; stage part 0 -----------
#pragma unroll
        for (int tm = 0; tm < 4; ++tm)
#pragma unroll
            for (int kk = 0; kk < 2; ++kk) {
                const int row = wm + tm * 16 + l15;
                const int ch = (kk * 4 + kq) ^ l7;
                af[tm][kk] = *(bf16x8*)(Ab + row * 128 + ch * 16);
            }
#pragma unroll
        for (int tn = 0; tn < 2; ++tn)
#pragma unroll
            for (int kk = 0; kk < 2; ++kk) {
                const int row = wn + tn * 16 + l15;
                const int ch = (kk * 4 + kq) ^ l7;
                bf[tn][kk] = *(bf16x8*)(Bb + row * 128 + ch * 16);
            }
        if (kt <= 13) STAGE_P0(bs);
        asm volatile("s_waitcnt lgkmcnt(0)" ::: "memory");
        __builtin_amdgcn_sched_barrier(0);
        __builtin_amdgcn_s_setprio(1);
#pragma unroll
        for (int tn = 0; tn < 2; ++tn)
#pragma unroll
            for (int tm = 0; tm < 4; ++tm)
#pragma unroll
                for (int kk = 0; kk < 2; ++kk)
                    acc[tm][tn] = __builtin_amdgcn_mfma_f32_16x16x32_bf16(
                        af[tm][kk], bf[tn][kk], acc[tm][tn], 0, 0, 0);
        __builtin_amdgcn_s_setprio(0);
        asm volatile("s_barrier" ::: "memory");
        __builtin_amdgcn_sched_barrier(0);
        // ---- phase 1: read B tn=2,3; stage part 1 -------------------------
#pragma unroll
        for (int tn = 0; tn < 2; ++tn)
#pragma unroll
            for (int kk = 0; kk < 2; ++kk) {
                const int row = wn + (tn + 2) * 16 + l15;
                const int ch = (kk * 4 + kq) ^ l7;
                bf[tn][kk] = *(bf16x8*)(Bb + row * 128 + ch * 16);
            }
        if (kt <= 13) STAGE_P1(bs);
        asm volatile("s_waitcnt lgkmcnt(0)" ::: "memory");
        __builtin_amdgcn_sched_barrier(0);
        __builtin_amdgcn_s_setprio(1);
#pragma unroll
        for (int tn = 0; tn < 2; ++tn)
#pragma unroll
            for (int tm = 0; tm < 4; ++tm)
#pragma unroll
                for (int kk = 0; kk < 2; ++kk)
                    acc[tm][tn + 2] = __builtin_amdgcn_mfma_f32_16x16x32_bf16(
                        af[tm][kk], bf[tn][kk], acc[tm][tn + 2], 0, 0, 0);
        __builtin_amdgcn_s_setprio(0);
        // no end barrier: next iter begins with vmcnt + s_barrier
    }

    // ---- epilogue: two 128-row passes via LDS transpose (tbuf = buf 0) -----
    // C/D map: col = lane&15, row = (lane>>4)*4 + reg. Pass p covers block
    // rows [128p,128p+128), written by waves 4p..4p+3 (wm in {128p,128p+64}).
    const int col = l15, rbase = (lane >> 4) * 4;
    __syncthreads();   // all frag reads done before tbuf overwrites buf 0
#pragma unroll
    for (int p = 0; p < 2; ++p) {
        if ((wave >> 2) == p) {
            const int lr = wm & 127;       // local 0 or 64
            if (z == 2) {
                // V: tbuf [d 0..127][tok 0..127]; key-granule perm on token.
#pragma unroll
                for (int tm = 0; tm < 4; ++tm)
#pragma unroll
                    for (int tn = 0; tn < 4; ++tn) {
                        const int dr = wn + tn * 16 + col;      // 0..127
                        const float bs2 = bias[nz * 128 + dr];
                        const int mi0 = lr + tm * 16 + rbase;   // 0..127 local
                        const int mip = (mi0 & ~12) | ((mi0 & 4) << 1) | ((mi0 & 8) >> 1);
                        unsigned short vals[4];
#pragma unroll
                        for (int r = 0; r < 4; ++r) vals[r] = f2bf(acc[tm][tn][r] + bs2);
                        *(ushort4*)&tbuf[dr * 136 + mip] = *(ushort4*)vals;
                    }
            } else {
                const float sc = (z == 0) ? SCALE_Q : 1.0f;
                // Q/K: tbuf [tok 0..127][n 0..127]
#pragma unroll
                for (int tm = 0; tm < 4; ++tm)
#pragma unroll
                    for (int tn = 0; tn < 4; ++tn) {
                        const int nn = wn + tn * 16 + col;      // 0..127
                        const float bs2 = bias[nz * 128 + nn];
                        const int mi0 = lr + tm * 16 + rbase;
#pragma unroll
                        for (int r = 0; r < 4; ++r)
                            tbuf[(mi0 + r) * 136 + nn] = f2bf((acc[tm][tn][r] + bs2) * sc);
                    }
            }
        }
        __syncthreads();
        // writeback: 512 threads, each one 64 B contiguous chunk
        if (z == 2) {
            const int dr = tid >> 2, seg = tid & 3;
            const int hh = nz * 2 + (dr >> 6), dd = dr & 63;
            const int mrow = m0 + p * 128;
            const int bb = mrow >> 11, tb = (mrow & (SEQ - 1)) >> 7;
            unsigned short* dst = O2 + (((size_t)bb * HEADS + hh) * HEAD_DIM + dd) * SEQ
                                     + tb * 128 + seg * 32;
            const unsigned short* srcl = &tbuf[dr * 136 + seg * 32];
#pragma unroll
            for (int i = 0; i < 4; ++i)
                *(uint4*)(dst + i * 8) = *(const uint4*)(srcl + i * 8);
        } else {
            unsigned short* O = (z == 0) ? O0 : O1;
            const int r = tid >> 2, seg = tid & 3;
            unsigned short* dst = O + (size_t)(m0 + p * 128 + r) * HIDDEN + nz * 128 + seg * 32;
            const unsigned short* srcl = &tbuf[r * 136 + seg * 32];
#pragma unroll
            for (int i = 0; i < 4; ++i)
                *(uint4*)(dst + i * 8) = *(const uint4*)(srcl + i * 8);
        }
        __syncthreads();   // tbuf reads done before next pass overwrites
    }
}

// ---- MFMA flash attention: 128 q/block, 2 waves, 64-key dbuf, 4 blk/CU -----
// grid 1024 (= 64 bh x 16 qc). TWO q-groups of 32 per wave; K/V LDS frags
// read ONCE feed BOTH groups. 2-wave blocks -> 4 independent blocks/CU.
// K-fragments for BOTH s32 sub-tiles hoisted right after the barrier.
// l accumulated on the VALU; epilogue redistributes per-query-row via shfl.
__global__ __launch_bounds__(128, 2) void attn_mfma(
    const unsigned short* __restrict__ Q, const unsigned short* __restrict__ K,
    const unsigned short* __restrict__ Vt, float* __restrict__ accp) {
    __shared__ unsigned short Klds[2][4096];  // 64 keys x 64 d, chunk-swizzled
    __shared__ unsigned short Vlds[2][4096];  // 64 d x 64 keys (perm), swizzled

    const int tid = threadIdx.x, lane = tid & 63, wave = tid >> 6;  // wave 0..1
    const int lq = lane & 31, g2 = lane >> 5;

    const int f = blockIdx.x;                 // 1024 = 64 bh x 16 qc
    const int bh = (f & 7) * 8 + ((f >> 3) & 7);
    const int qc = f >> 6;                    // 0..15 (128-q chunk)
    const int b = bh >> 4, h = bh & 15;

    // Q B-fragments: 2 groups of 32 q per wave, 4 k-slices each
    bf16x8 qfrag[2][4];
#pragma unroll
    for (int grp = 0; grp < 2; ++grp) {
        const size_t qb = ((size_t)(b * SEQ + qc * 128 + wave * 64 + grp * 32 + lq)) * HIDDEN
                          + h * HEAD_DIM + g2 * 8;
#pragma unroll
        for (int ds = 0; ds < 4; ++ds) qfrag[grp][ds] = *(const bf16x8*)&Q[qb + ds * 16];
    }

    // staging pointers. K: wave w covers rows [32w,32w+32) (4 instr x 8 rows);
    // V: d-rows [32w,32w+32). XOR chunk swizzle baked into the GLOBAL address.
    const unsigned short* kg[4];
    const unsigned short* vg[4];
    {
        const int kr = lane >> 3;                       // 0..7
        const int kc = ((lane & 7) ^ kr) * 8;
#pragma unroll
        for (int j = 0; j < 4; ++j)
            kg[j] = K + ((size_t)(b * SEQ + wave * 32 + j * 8 + kr)) * HIDDEN + h * HEAD_DIM + kc;
#pragma unroll
        for (int j = 0; j < 4; ++j) {
            const int dl = wave * 32 + j * 8 + (lane >> 3);
            const int cc = ((lane & 7) ^ (dl & 7)) * 8;
            vg[j] = Vt + ((size_t)bh * HEAD_DIM + dl) * SEQ + cc;
        }
    }

    floatx16 oacc[2][2];                      // [grp][nf]
#pragma unroll
    for (int r = 0; r < 16; ++r) {
        oacc[0][0][r] = 0.f; oacc[0][1][r] = 0.f;
        oacc[1][0][r] = 0.f; oacc[1][1][r] = 0.f;
    }
    float lsum00 = 0.f, lsum01 = 0.f, lsum10 = 0.f, lsum11 = 0.f;

    // prologue: stage tile 0 into buf 0
#pragma unroll
    for (int j = 0; j < 4; ++j) {
        async_cp16(kg[j], (char*)Klds[0] + (wave * 32 + j * 8) * 128);
        async_cp16(vg[j], (char*)Vlds[0] + (wave * 32 + j * 8) * 128);
        kg[j] += 64 * HIDDEN; vg[j] += 64;
    }
    __syncthreads();

    for (int it = 0; it < 32; ++it) {
        const int cur = it & 1;
        if (it < 31) {
#pragma unroll
            for (int j = 0; j < 4; ++j) {
                async_cp16(kg[j], (char*)Klds[cur ^ 1] + (wave * 32 + j * 8) * 128);
                async_cp16(vg[j], (char*)Vlds[cur ^ 1] + (wave * 32 + j * 8) * 128);
                kg[j] += 64 * HIDDEN; vg[j] += 64;
            }
        }
        // --- hoisted K-fragment reads for BOTH 32-key sub-tiles -------------
        bf16x8 kfa[2][4];
#pragma unroll
        for (int s32 = 0; s32 < 2; ++s32)
#pragma unroll
            for (int ds = 0; ds < 4; ++ds)
                kfa[s32][ds] = *(bf16x8*)((char*)Klds[cur] + (s32 * 32 + lq) * 128
                                          + (((g2 + 2 * ds) ^ (lq & 7)) * 16));
#pragma unroll
        for (int s32 = 0; s32 < 2; ++s32) {
            floatx16 sacc0, sacc1;
#pragma unroll
            for (int r = 0; r < 16; ++r) { sacc0[r] = 0.f; sacc1[r] = 0.f; }
#pragma unroll
            for (int ds = 0; ds < 4; ++ds)
                sacc0 = __builtin_amdgcn_mfma_f32_32x32x16_bf16(kfa[s32][ds], qfrag[0][ds], sacc0, 0, 0, 0);
#pragma unroll
            for (int ds = 0; ds < 4; ++ds)
                sacc1 = __builtin_amdgcn_mfma_f32_32x32x16_bf16(kfa[s32][ds], qfrag[1][ds], sacc1, 0, 0, 0);

            bf16x8 vf[2][2];                 // [ks2][nf]
#pragma unroll
            for (int ks2 = 0; ks2 < 2; ++ks2)
#pragma unroll
                for (int nf = 0; nf < 2; ++nf) {
                    const int d = nf * 32 + lq;
                    const int c = (2 * (s32 * 2 + ks2) + g2) ^ (d & 7);
                    vf[ks2][nf] = *(bf16x8*)((char*)Vlds[cur] + d * 128 + c * 16);
                }

            unsigned pk[2][8];
#pragma unroll
            for (int j = 0; j < 8; ++j) {
                union { float f; unsigned u; } plo, phi;
                plo.f = fast_exp2(sacc0[2 * j]);
                phi.f = fast_exp2(sacc0[2 * j + 1]);
                lsum00 += plo.f; lsum01 += phi.f;
                pk[0][j] = __builtin_amdgcn_perm(phi.u, plo.u, 0x07060302u);
            }
#pragma unroll
            for (int j = 0; j < 8; ++j) {
                union { float f; unsigned u; } plo, phi;
                plo.f = fast_exp2(sacc1[2 * j]);
                phi.f = fast_exp2(sacc1[2 * j + 1]);
                lsum10 += plo.f; lsum11 += phi.f;
                pk[1][j] = __builtin_amdgcn_perm(phi.u, plo.u, 0x07060302u);
            }

#pragma unroll
            for (int ks2 = 0; ks2 < 2; ++ks2)
#pragma unroll
                for (int grp = 0; grp < 2; ++grp) {
                    union { uint4 u; bf16x8 v; } af;
                    af.u.x = pk[grp][4 * ks2];
                    af.u.y = pk[grp][4 * ks2 + 1];
                    af.u.z = pk[grp][4 * ks2 + 2];
                    af.u.w = pk[grp][4 * ks2 + 3];
#pragma unroll
                    for (int nf = 0; nf < 2; ++nf)
                        oacc[grp][nf] = __builtin_amdgcn_mfma_f32_32x32x16_bf16(af.v, vf[ks2][nf], oacc[grp][nf], 0, 0, 0);
                }
        }
        if (it < 31) __syncthreads();
    }

    // epilogue: combine l partials, redistribute per-query-row, accumulate
    float linv[2][16];
#pragma unroll
    for (int grp = 0; grp < 2; ++grp) {
        float lf = (grp == 0) ? (lsum00 + lsum01) : (lsum10 + lsum11);
        lf += __shfl_xor(lf, 32, 64);
#pragma unroll
        for (int r = 0; r < 16; ++r) {
            const int qr = (r & 3) + 8 * (r >> 2) + 4 * g2;
            linv[grp][r] = 1.0f / __shfl(lf, qr, 64);
        }
    }
#pragma unroll
    for (int nf = 0; nf < 2; ++nf) {
        float v = 0.f;
#pragma unroll
        for (int r = 0; r < 16; ++r)
            v += oacc[0][nf][r] * linv[0][r] + oacc[1][nf][r] * linv[1][r];
        v += __shfl_xor(v, 32, 64);
        if (lane < 32)
            atomicAdd(&accp[b * HIDDEN + h * HEAD_DIM + nf * 32 + lq], v);
    }
}

// ---- final projection: out = (acc/T) @ Wo^T + bo ---------------------------
__global__ __launch_bounds__(256) void out_proj(const float* __restrict__ acc,
                                                const float* __restrict__ Wo,
                                                const float* __restrict__ bo,
                                                float* __restrict__ out) {
    const int tid = threadIdx.x;
    const int nl = tid >> 6, lane = tid & 63;
    const int n = blockIdx.x * 4 + nl;
    const float* wr = Wo + (size_t)n * HIDDEN + lane * 16;
    float s0 = 0.f, s1 = 0.f, s2 = 0.f, s3 = 0.f;
#pragma unroll
    for (int kk = 0; kk < 4; ++kk) {
        float4 w = *(const float4*)(wr + kk * 4);
        float4 a0 = *(const float4*)(acc + 0 * HIDDEN + lane * 16 + kk * 4);
        float4 a1 = *(const float4*)(acc + 1 * HIDDEN + lane * 16 + kk * 4);
        float4 a2 = *(const float4*)(acc + 2 * HIDDEN + lane * 16 + kk * 4);
        float4 a3 = *(const float4*)(acc + 3 * HIDDEN + lane * 16 + kk * 4);
        s0 += w.x * a0.x + w.y * a0.y + w.z * a0.z + w.w * a0.w;
        s1 += w.x * a1.x + w.y * a1.y + w.z * a1.z + w.w * a1.w;
        s2 += w.x * a2.x + w.y * a2.y + w.z * a2.z + w.w * a2.w;
        s3 += w.x * a3.x + w.y * a3.y + w.z * a3.z + w.w * a3.w;
    }
#pragma unroll
    for (int off = 32; off; off >>= 1) {
        s0 += __shfl_xor(s0, off, 64);
        s1 += __shfl_xor(s1, off, 64);
        s2 += __shfl_xor(s2, off, 64);
        s3 += __shfl_xor(s3, off, 64);
    }
    if (lane < 4) {
        float sv = (lane == 0) ? s0 : (lane == 1) ? s1 : (lane == 2) ? s2 : s3;
        out[lane * HIDDEN + n] = sv * (1.0f / (float)SEQ) + bo[n];
    }
}

extern "C" void kernel_launch(void* const* d_in, const int* in_sizes, int n_in,
                              void* d_out, int out_size, void* d_ws, size_t ws_size,
                              hipStream_t stream) {
    const float* x  = (const float*)d_in[0];
    const float* Wq = (const float*)d_in[1];
    const float* bq = (const float*)d_in[2];
    const float* Wk = (const float*)d_in[3];
    const float* bk = (const float*)d_in[4];
    const float* Wv = (const float*)d_in[5];
    const float* bv = (const float*)d_in[6];
    const float* Wo = (const float*)d_in[7];
    const float* bo = (const float*)d_in[8];
    float* out = (float*)d_out;

    char* ws = (char*)d_ws;
    unsigned short* x_bf  = (unsigned short*)(ws);                      // 16 MB
    unsigned short* wq_bf = (unsigned short*)(ws + 16777216);           //  2 MB
    unsigned short* wk_bf = (unsigned short*)(ws + 18874368);           //  2 MB
    unsigned short* wv_bf = (unsigned short*)(ws + 20971520);           //  2 MB
    unsigned short* q_bf  = (unsigned short*)(ws + 23068672);           // 16 MB (pre-scaled Q)
    unsigned short* k_bf  = (unsigned short*)(ws + 39845888);           // 16 MB
    unsigned short* vt_bf = (unsigned short*)(ws + 56623104);           // 16 MB (V^T, granule-perm)
    float*          accp  = (float*)(ws + 73400320);                    // 16 KB

    // 144 KB dynamic LDS for the 3-buffer qkv pipeline
    hipFuncSetAttribute((const void*)qkv_gemm,
                        hipFuncAttributeMaxDynamicSharedMemorySize, 147456);

    conv_all<<<dim3(8192 + 3072), dim3(256), 0, stream>>>(
        x, Wq, Wk, Wv, x_bf, wq_bf, wk_bf, wv_bf, accp);

    qkv_gemm<<<dim3(768), dim3(512), 147456, stream>>>(
        x_bf, wq_bf, wk_bf, wv_bf, bq, bk, bv, q_bf, k_bf, vt_bf);

    attn_mfma<<<dim3(1024), dim3(128), 0, stream>>>(q_bf, k_bf, vt_bf, accp);

    out_proj<<<dim3(256), dim3(256), 0, stream>>>(accp, Wo, bo, out);
}

// Round 12
// 243.081 us; speedup vs baseline: 1.0123x; 1.0123x over previous
//
#include <hip/hip_runtime.h>
#include <stdint.h>

#define HIDDEN 1024
#define HEADS 16
#define HEAD_DIM 64
#define BATCH 4
#define SEQ 2048
#define NTOK (BATCH * SEQ)   // 8192

typedef __attribute__((ext_vector_type(8))) short bf16x8;
typedef __attribute__((ext_vector_type(4))) float floatx4;
typedef __attribute__((ext_vector_type(16))) float floatx16;

// log2(e) / sqrt(HEAD_DIM) : folded into Q so p = exp2(s) directly
#define SCALE_Q 0.18033688011112042f

__device__ __forceinline__ unsigned short f2bf(float f) {
    union { float f; unsigned u; } x; x.f = f;
    unsigned r = x.u + 0x7fffu + ((x.u >> 16) & 1u);
    return (unsigned short)(r >> 16);
}

__device__ __forceinline__ float fast_exp2(float x) {
#if __has_builtin(__builtin_amdgcn_exp2f)
    return __builtin_amdgcn_exp2f(x);
#else
    return exp2f(x);
#endif
}

typedef __attribute__((address_space(3))) unsigned int lds_u32;
typedef const __attribute__((address_space(1))) unsigned int gl_u32;

// async global->LDS, 16B per lane; l is the WAVE-UNIFORM base (HW scatters
// lane i's 16B to l + i*16).
__device__ __forceinline__ void async_cp16(const void* g, void* l) {
#if __has_builtin(__builtin_amdgcn_global_load_lds)
    __builtin_amdgcn_global_load_lds((gl_u32*)g, (lds_u32*)l, 16, 0, 0);
#else
    *(uint4*)((char*)l + (threadIdx.x & 63) * 16) = *(const uint4*)g;
#endif
}

// ---- fused fp32->bf16 conversion for x, Wq, Wk, Wv + zero of accp ----------
__global__ __launch_bounds__(256) void conv_all(
    const float* __restrict__ x, const float* __restrict__ Wq,
    const float* __restrict__ Wk, const float* __restrict__ Wv,
    unsigned short* __restrict__ x_bf, unsigned short* __restrict__ wq_bf,
    unsigned short* __restrict__ wk_bf, unsigned short* __restrict__ wv_bf,
    float* __restrict__ accp) {
    const int blk = blockIdx.x, tid = threadIdx.x;
    const float* src;
    unsigned short* dst;
    size_t i;
    if (blk < 8192) {
        src = x; dst = x_bf; i = (size_t)blk * 256 + tid;
        if (blk < 16) accp[blk * 256 + tid] = 0.0f;
    } else {
        int r = blk - 8192;
        int s = r >> 10;
        src = (s == 0) ? Wq : (s == 1) ? Wk : Wv;
        dst = (s == 0) ? wq_bf : (s == 1) ? wk_bf : wv_bf;
        i = (size_t)(r & 1023) * 256 + tid;
    }
    float4 v = *(const float4*)(src + 4 * i);
    unsigned short o[4];
    o[0] = f2bf(v.x); o[1] = f2bf(v.y); o[2] = f2bf(v.z); o[3] = f2bf(v.w);
    *(ushort4*)(dst + 4 * i) = *(ushort4*)o;
}

// ---- QKV GEMM: phase-interleaved schedule (T2+T3+T4+T5 port) ---------------
// Tile 256x128, BK=64, 8 waves (512 thr), wave tile 64x64 (4M x 2N wave grid).
// grid 768 = 24 nzb x 32 mb = 3 clean rounds of 256 CUs. LDS: 3 bufs x 48K =
// 144 KB dynamic -> depth-2 prefetch, counted vmcnt(6) in-loop.
// Per K-tile: 2 phases, each {ds_read subtile || issue 3 global_load_lds ||
// lgkmcnt(0) || setprio-wrapped 16xMFMA || barrier}. 8-chunk XOR swizzle
// both-sides (pre-swizzled global source + swizzled ds_read).
// r11 measured: <=76.9 us (off top-5), ~par-or-better vs r7's 78.2 2-phase.
// Epilogue: two 128-row transpose passes via tbuf (aliases buf 0).
// z==0 (Q): scaled by SCALE_Q.  z==2 (V): transposed output Vt[bh*64+d][t]
// with key-granule PERMUTATION (swap bits 2,3 of local token idx).
__global__ __launch_bounds__(512, 2) void qkv_gemm(
    const unsigned short* __restrict__ X,
    const unsigned short* __restrict__ W0, const unsigned short* __restrict__ W1,
    const unsigned short* __restrict__ W2,
    const float* __restrict__ b0, const float* __restrict__ b1,
    const float* __restrict__ b2,
    unsigned short* __restrict__ O0, unsigned short* __restrict__ O1,
    unsigned short* __restrict__ O2) {
    extern __shared__ __align__(16) char smem[];   // 3 x 49152
    unsigned short* tbuf = (unsigned short*)smem;  // epilogue aliases buf 0

    const int id = blockIdx.x;
    const int mb = id & 31, nzb = id >> 5;
    const int z = nzb >> 3, nz = nzb & 7;
    const int m0 = mb * 256;
    const unsigned short* W = (z == 0) ? W0 : (z == 1) ? W1 : W2;
    const float* bias       = (z == 0) ? b0 : (z == 1) ? b1 : b2;

    const int tid = threadIdx.x, lane = tid & 63, wave = tid >> 6;  // 0..7
    const int wm = (wave >> 1) * 64;          // 0,64,128,192
    const int wn = (wave & 1) * 64;           // 0,64
    const int l15 = lane & 15, l7 = lane & 7, kq = lane >> 4;

    // staging: global col chunk = (lane&7) ^ (lane>>3)  (row&7 == lane>>3)
    const int sxc = ((lane & 7) ^ (lane >> 3)) * 8;   // shorts
    const unsigned short* ga[4];
    const unsigned short* gb[2];
#pragma unroll
    for (int j = 0; j < 4; ++j)
        ga[j] = X + (size_t)(m0 + wave * 32 + j * 8 + (lane >> 3)) * HIDDEN + sxc;
#pragma unroll
    for (int j = 0; j < 2; ++j)
        gb[j] = W + (size_t)(nz * 128 + wave * 16 + j * 8 + (lane >> 3)) * HIDDEN + sxc;

    floatx4 acc[4][4];
#pragma unroll
    for (int tm = 0; tm < 4; ++tm)
#pragma unroll
        for (int tn = 0; tn < 4; ++tn)
#pragma unroll
            for (int r = 0; r < 4; ++r) acc[tm][tn][r] = 0.f;

    auto STAGE_P0 = [&](int s) {
        char* base = smem + s * 49152;
        async_cp16(ga[0], base + (wave * 32 + 0) * 128);
        async_cp16(ga[1], base + (wave * 32 + 8) * 128);
        async_cp16(gb[0], base + 32768 + (wave * 16 + 0) * 128);
    };
    auto STAGE_P1 = [&](int s) {   // also advances pointers by one K-tile
        char* base = smem + s * 49152;
        async_cp16(ga[2], base + (wave * 32 + 16) * 128);
        async_cp16(ga[3], base + (wave * 32 + 24) * 128);
        async_cp16(gb[1], base + 32768 + (wave * 16 + 8) * 128);
#pragma unroll
        for (int j = 0; j < 4; ++j) ga[j] += 64;
        gb[0] += 64; gb[1] += 64;
    };

    // prologue: tiles 0,1 into bufs 0,1 (12 loads in flight, no wait)
    STAGE_P0(0); STAGE_P1(0);
    STAGE_P0(1); STAGE_P1(1);

    for (int kt = 0; kt < 16; ++kt) {
        const int c = kt % 3;              // compute buf
        const int bs = (kt + 2) % 3;       // stage buf (tile kt+2)
        // tile kt landed (6 newer loads stay in flight across the barrier)
        if (kt < 15) { asm volatile("s_waitcnt vmcnt(6)" ::: "memory"); }
        else         { asm volatile("s_waitcnt vmcnt(0)" ::: "memory"); }
        __builtin_amdgcn_sched_barrier(0);
        asm volatile("s_barrier" ::: "memory");
        __builtin_amdgcn_sched_barrier(0);

        const char* Ab = smem + c * 49152;
        const char* Bb = Ab + 32768;
        bf16x8 af[4][2], bf[2][2];
        // ---- phase 0: read all A frags + B tn=0,1; stage part 0 -----------
#pragma unroll
        for (int tm = 0; tm < 4; ++tm)
#pragma unroll
            for (int kk = 0; kk < 2; ++kk) {
                const int row = wm + tm * 16 + l15;
                const int ch = (kk * 4 + kq) ^ l7;
                af[tm][kk] = *(bf16x8*)(Ab + row * 128 + ch * 16);
            }
#pragma unroll
        for (int tn = 0; tn < 2; ++tn)
#pragma unroll
            for (int kk = 0; kk < 2; ++kk) {
                const int row = wn + tn * 16 + l15;
                const int ch = (kk * 4 + kq) ^ l7;
                bf[tn][kk] = *(bf16x8*)(Bb + row * 128 + ch * 16);
            }
        if (kt <= 13) STAGE_P0(bs);
        asm volatile("s_waitcnt lgkmcnt(0)" ::: "memory");
        __builtin_amdgcn_sched_barrier(0);
        __builtin_amdgcn_s_setprio(1);
#pragma unroll
        for (int tn = 0; tn < 2; ++tn)
#pragma unroll
            for (int tm = 0; tm < 4; ++tm)
#pragma unroll
                for (int kk = 0; kk < 2; ++kk)
                    acc[tm][tn] = __builtin_amdgcn_mfma_f32_16x16x32_bf16(
                        af[tm][kk], bf[tn][kk], acc[tm][tn], 0, 0, 0);
        __builtin_amdgcn_s_setprio(0);
        asm volatile("s_barrier" ::: "memory");
        __builtin_amdgcn_sched_barrier(0);
        // ---- phase 1: read B tn=2,3; stage part 1 -------------------------
#pragma unroll
        for (int tn = 0; tn < 2; ++tn)
#pragma unroll
            for (int kk = 0; kk < 2; ++kk) {
                const int row = wn + (tn + 2) * 16 + l15;
                const int ch = (kk * 4 + kq) ^ l7;
                bf[tn][kk] = *(bf16x8*)(Bb + row * 128 + ch * 16);
            }
        if (kt <= 13) STAGE_P1(bs);
        asm volatile("s_waitcnt lgkmcnt(0)" ::: "memory");
        __builtin_amdgcn_sched_barrier(0);
        __builtin_amdgcn_s_setprio(1);
#pragma unroll
        for (int tn = 0; tn < 2; ++tn)
#pragma unroll
            for (int tm = 0; tm < 4; ++tm)
#pragma unroll
                for (int kk = 0; kk < 2; ++kk)
                    acc[tm][tn + 2] = __builtin_amdgcn_mfma_f32_16x16x32_bf16(
                        af[tm][kk], bf[tn][kk], acc[tm][tn + 2], 0, 0, 0);
        __builtin_amdgcn_s_setprio(0);
        // no end barrier: next iter begins with vmcnt + s_barrier
    }

    // ---- epilogue: two 128-row passes via LDS transpose (tbuf = buf 0) -----
    // C/D map: col = lane&15, row = (lane>>4)*4 + reg. Pass p covers block
    // rows [128p,128p+128), written by waves 4p..4p+3 (wm in {128p,128p+64}).
    const int col = l15, rbase = (lane >> 4) * 4;
    __syncthreads();   // all frag reads done before tbuf overwrites buf 0
#pragma unroll
    for (int p = 0; p < 2; ++p) {
        if ((wave >> 2) == p) {
            const int lr = wm & 127;       // local 0 or 64
            if (z == 2) {
                // V: tbuf [d 0..127][tok 0..127]; key-granule perm on token.
#pragma unroll
                for (int tm = 0; tm < 4; ++tm)
#pragma unroll
                    for (int tn = 0; tn < 4; ++tn) {
                        const int dr = wn + tn * 16 + col;      // 0..127
                        const float bs2 = bias[nz * 128 + dr];
                        const int mi0 = lr + tm * 16 + rbase;   // 0..127 local
                        const int mip = (mi0 & ~12) | ((mi0 & 4) << 1) | ((mi0 & 8) >> 1);
                        unsigned short vals[4];
#pragma unroll
                        for (int r = 0; r < 4; ++r) vals[r] = f2bf(acc[tm][tn][r] + bs2);
                        *(ushort4*)&tbuf[dr * 136 + mip] = *(ushort4*)vals;
                    }
            } else {
                const float sc = (z == 0) ? SCALE_Q : 1.0f;
                // Q/K: tbuf [tok 0..127][n 0..127]
#pragma unroll
                for (int tm = 0; tm < 4; ++tm)
#pragma unroll
                    for (int tn = 0; tn < 4; ++tn) {
                        const int nn = wn + tn * 16 + col;      // 0..127
                        const float bs2 = bias[nz * 128 + nn];
                        const int mi0 = lr + tm * 16 + rbase;
#pragma unroll
                        for (int r = 0; r < 4; ++r)
                            tbuf[(mi0 + r) * 136 + nn] = f2bf((acc[tm][tn][r] + bs2) * sc);
                    }
            }
        }
        __syncthreads();
        // writeback: 512 threads, each one 64 B contiguous chunk
        if (z == 2) {
            const int dr = tid >> 2, seg = tid & 3;
            const int hh = nz * 2 + (dr >> 6), dd = dr & 63;
            const int mrow = m0 + p * 128;
            const int bb = mrow >> 11, tb = (mrow & (SEQ - 1)) >> 7;
            unsigned short* dst = O2 + (((size_t)bb * HEADS + hh) * HEAD_DIM + dd) * SEQ
                                     + tb * 128 + seg * 32;
            const unsigned short* srcl = &tbuf[dr * 136 + seg * 32];
#pragma unroll
            for (int i = 0; i < 4; ++i)
                *(uint4*)(dst + i * 8) = *(const uint4*)(srcl + i * 8);
        } else {
            unsigned short* O = (z == 0) ? O0 : O1;
            const int r = tid >> 2, seg = tid & 3;
            unsigned short* dst = O + (size_t)(m0 + p * 128 + r) * HIDDEN + nz * 128 + seg * 32;
            const unsigned short* srcl = &tbuf[r * 136 + seg * 32];
#pragma unroll
            for (int i = 0; i < 4; ++i)
                *(uint4*)(dst + i * 8) = *(const uint4*)(srcl + i * 8);
        }
        __syncthreads();   // tbuf reads done before next pass overwrites
    }
}

// ---- MFMA flash attention: 128 q/block, 2 waves, 64-key dbuf, 4 blk/CU -----
// grid 1024 (= 64 bh x 16 qc). TWO q-groups of 32 per wave; K/V LDS frags
// read ONCE feed BOTH groups. 2-wave blocks -> 4 independent blocks/CU.
// r12: the two s32 sub-tiles are MERGED: all 16 QK MFMAs issue first as 4
// independent round-robin chains (setprio-wrapped), then exp(s32=0) runs
// while QK(s32=1) drains, and exp(s32=1) overlaps PV(s32=0) execution --
// removing the QK->exp and exp->PV serialization bubbles (counters r11:
// MfmaUtil 38.5 + VALUBusy 44.2 = 83% additive, 2 waves/SIMD grid-capped).
// l accumulated on the VALU; epilogue redistributes per-query-row via shfl.
__global__ __launch_bounds__(128, 2) void attn_mfma(
    const unsigned short* __restrict__ Q, const unsigned short* __restrict__ K,
    const unsigned short* __restrict__ Vt, float* __restrict__ accp) {
    __shared__ unsigned short Klds[2][4096];  // 64 keys x 64 d, chunk-swizzled
    __shared__ unsigned short Vlds[2][4096];  // 64 d x 64 keys (perm), swizzled

    const int tid = threadIdx.x, lane = tid & 63, wave = tid >> 6;  // wave 0..1
    const int lq = lane & 31, g2 = lane >> 5;

    const int f = blockIdx.x;                 // 1024 = 64 bh x 16 qc
    const int bh = (f & 7) * 8 + ((f >> 3) & 7);
    const int qc = f >> 6;                    // 0..15 (128-q chunk)
    const int b = bh >> 4, h = bh & 15;

    // Q B-fragments: 2 groups of 32 q per wave, 4 k-slices each
    bf16x8 qfrag[2][4];
#pragma unroll
    for (int grp = 0; grp < 2; ++grp) {
        const size_t qb = ((size_t)(b * SEQ + qc * 128 + wave * 64 + grp * 32 + lq)) * HIDDEN
                          + h * HEAD_DIM + g2 * 8;
#pragma unroll
        for (int ds = 0; ds < 4; ++ds) qfrag[grp][ds] = *(const bf16x8*)&Q[qb + ds * 16];
    }

    // staging pointers. K: wave w covers rows [32w,32w+32) (4 instr x 8 rows);
    // V: d-rows [32w,32w+32). XOR chunk swizzle baked into the GLOBAL address.
    const unsigned short* kg[4];
    const unsigned short* vg[4];
    {
        const int kr = lane >> 3;                       // 0..7
        const int kc = ((lane & 7) ^ kr) * 8;
#pragma unroll
        for (int j = 0; j < 4; ++j)
            kg[j] = K + ((size_t)(b * SEQ + wave * 32 + j * 8 + kr)) * HIDDEN + h * HEAD_DIM + kc;
#pragma unroll
        for (int j = 0; j < 4; ++j) {
            const int dl = wave * 32 + j * 8 + (lane >> 3);
            const int cc = ((lane & 7) ^ (dl & 7)) * 8;
            vg[j] = Vt + ((size_t)bh * HEAD_DIM + dl) * SEQ + cc;
        }
    }

    floatx16 oacc[2][2];                      // [grp][nf]
#pragma unroll
    for (int r = 0; r < 16; ++r) {
        oacc[0][0][r] = 0.f; oacc[0][1][r] = 0.f;
        oacc[1][0][r] = 0.f; oacc[1][1][r] = 0.f;
    }
    float lsum00 = 0.f, lsum01 = 0.f, lsum10 = 0.f, lsum11 = 0.f;

    // prologue: stage tile 0 into buf 0
#pragma unroll
    for (int j = 0; j < 4; ++j) {
        async_cp16(kg[j], (char*)Klds[0] + (wave * 32 + j * 8) * 128);
        async_cp16(vg[j], (char*)Vlds[0] + (wave * 32 + j * 8) * 128);
        kg[j] += 64 * HIDDEN; vg[j] += 64;
    }
    __syncthreads();

    for (int it = 0; it < 32; ++it) {
        const int cur = it & 1;
        if (it < 31) {
#pragma unroll
            for (int j = 0; j < 4; ++j) {
                async_cp16(kg[j], (char*)Klds[cur ^ 1] + (wave * 32 + j * 8) * 128);
                async_cp16(vg[j], (char*)Vlds[cur ^ 1] + (wave * 32 + j * 8) * 128);
                kg[j] += 64 * HIDDEN; vg[j] += 64;
            }
        }
        // --- hoisted K-fragment reads for BOTH 32-key sub-tiles -------------
        bf16x8 kfa[2][4];
#pragma unroll
        for (int s32 = 0; s32 < 2; ++s32)
#pragma unroll
            for (int ds = 0; ds < 4; ++ds)
                kfa[s32][ds] = *(bf16x8*)((char*)Klds[cur] + (s32 * 32 + lq) * 128
                                          + (((g2 + 2 * ds) ^ (lq & 7)) * 16));

        // --- QK^T: 4 independent chains (s32 x grp), round-robin issue ------
        floatx16 sacc[2][2];
#pragma unroll
        for (int r = 0; r < 16; ++r) {
            sacc[0][0][r] = 0.f; sacc[0][1][r] = 0.f;
            sacc[1][0][r] = 0.f; sacc[1][1][r] = 0.f;
        }
        __builtin_amdgcn_s_setprio(1);
#pragma unroll
        for (int ds = 0; ds < 4; ++ds) {
            sacc[0][0] = __builtin_amdgcn_mfma_f32_32x32x16_bf16(kfa[0][ds], qfrag[0][ds], sacc[0][0], 0, 0, 0);
            sacc[0][1] = __builtin_amdgcn_mfma_f32_32x32x16_bf16(kfa[0][ds], qfrag[1][ds], sacc[0][1], 0, 0, 0);
            sacc[1][0] = __builtin_amdgcn_mfma_f32_32x32x16_bf16(kfa[1][ds], qfrag[0][ds], sacc[1][0], 0, 0, 0);
            sacc[1][1] = __builtin_amdgcn_mfma_f32_32x32x16_bf16(kfa[1][ds], qfrag[1][ds], sacc[1][1], 0, 0, 0);
        }
        __builtin_amdgcn_s_setprio(0);

        // --- per s32: V reads, exp/pack (overlaps other s32's MFMAs), PV ----
#pragma unroll
        for (int s32 = 0; s32 < 2; ++s32) {
            bf16x8 vf[2][2];                 // [ks2][nf]
#pragma unroll
            for (int ks2 = 0; ks2 < 2; ++ks2)
#pragma unroll
                for (int nf = 0; nf < 2; ++nf) {
                    const int d = nf * 32 + lq;
                    const int c = (2 * (s32 * 2 + ks2) + g2) ^ (d & 7);
                    vf[ks2][nf] = *(bf16x8*)((char*)Vlds[cur] + d * 128 + c * 16);
                }

            unsigned pk[2][8];
#pragma unroll
            for (int j = 0; j < 8; ++j) {
                union { float f; unsigned u; } plo, phi;
                plo.f = fast_exp2(sacc[s32][0][2 * j]);
                phi.f = fast_exp2(sacc[s32][0][2 * j + 1]);
                lsum00 += plo.f; lsum01 += phi.f;
                pk[0][j] = __builtin_amdgcn_perm(phi.u, plo.u, 0x07060302u);
            }
#pragma unroll
            for (int j = 0; j < 8; ++j) {
                union { float f; unsigned u; } plo, phi;
                plo.f = fast_exp2(sacc[s32][1][2 * j]);
                phi.f = fast_exp2(sacc[s32][1][2 * j + 1]);
                lsum10 += plo.f; lsum11 += phi.f;
                pk[1][j] = __builtin_amdgcn_perm(phi.u, plo.u, 0x07060302u);
            }

            __builtin_amdgcn_s_setprio(1);
#pragma unroll
            for (int ks2 = 0; ks2 < 2; ++ks2)
#pragma unroll
                for (int grp = 0; grp < 2; ++grp) {
                    union { uint4 u; bf16x8 v; } af;
                    af.u.x = pk[grp][4 * ks2];
                    af.u.y = pk[grp][4 * ks2 + 1];
                    af.u.z = pk[grp][4 * ks2 + 2];
                    af.u.w = pk[grp][4 * ks2 + 3];
#pragma unroll
                    for (int nf = 0; nf < 2; ++nf)
                        oacc[grp][nf] = __builtin_amdgcn_mfma_f32_32x32x16_bf16(af.v, vf[ks2][nf], oacc[grp][nf], 0, 0, 0);
                }
            __builtin_amdgcn_s_setprio(0);
        }
        if (it < 31) __syncthreads();
    }

    // epilogue: combine l partials, redistribute per-query-row, accumulate
    float linv[2][16];
#pragma unroll
    for (int grp = 0; grp < 2; ++grp) {
        float lf = (grp == 0) ? (lsum00 + lsum01) : (lsum10 + lsum11);
        lf += __shfl_xor(lf, 32, 64);
#pragma unroll
        for (int r = 0; r < 16; ++r) {
            const int qr = (r & 3) + 8 * (r >> 2) + 4 * g2;
            linv[grp][r] = 1.0f / __shfl(lf, qr, 64);
        }
    }
#pragma unroll
    for (int nf = 0; nf < 2; ++nf) {
        float v = 0.f;
#pragma unroll
        for (int r = 0; r < 16; ++r)
            v += oacc[0][nf][r] * linv[0][r] + oacc[1][nf][r] * linv[1][r];
        v += __shfl_xor(v, 32, 64);
        if (lane < 32)
            atomicAdd(&accp[b * HIDDEN + h * HEAD_DIM + nf * 32 + lq], v);
    }
}

// ---- final projection: out = (acc/T) @ Wo^T + bo ---------------------------
__global__ __launch_bounds__(256) void out_proj(const float* __restrict__ acc,
                                                const float* __restrict__ Wo,
                                                const float* __restrict__ bo,
                                                float* __restrict__ out) {
    const int tid = threadIdx.x;
    const int nl = tid >> 6, lane = tid & 63;
    const int n = blockIdx.x * 4 + nl;
    const float* wr = Wo + (size_t)n * HIDDEN + lane * 16;
    float s0 = 0.f, s1 = 0.f, s2 = 0.f, s3 = 0.f;
#pragma unroll
    for (int kk = 0; kk < 4; ++kk) {
        float4 w = *(const float4*)(wr + kk * 4);
        float4 a0 = *(const float4*)(acc + 0 * HIDDEN + lane * 16 + kk * 4);
        float4 a1 = *(const float4*)(acc + 1 * HIDDEN + lane * 16 + kk * 4);
        float4 a2 = *(const float4*)(acc + 2 * HIDDEN + lane * 16 + kk * 4);
        float4 a3 = *(const float4*)(acc + 3 * HIDDEN + lane * 16 + kk * 4);
        s0 += w.x * a0.x + w.y * a0.y + w.z * a0.z + w.w * a0.w;
        s1 += w.x * a1.x + w.y * a1.y + w.z * a1.z + w.w * a1.w;
        s2 += w.x * a2.x + w.y * a2.y + w.z * a2.z + w.w * a2.w;
        s3 += w.x * a3.x + w.y * a3.y + w.z * a3.z + w.w * a3.w;
    }
#pragma unroll
    for (int off = 32; off; off >>= 1) {
        s0 += __shfl_xor(s0, off, 64);
        s1 += __shfl_xor(s1, off, 64);
        s2 += __shfl_xor(s2, off, 64);
        s3 += __shfl_xor(s3, off, 64);
    }
    if (lane < 4) {
        float sv = (lane == 0) ? s0 : (lane == 1) ? s1 : (lane == 2) ? s2 : s3;
        out[lane * HIDDEN + n] = sv * (1.0f / (float)SEQ) + bo[n];
    }
}

extern "C" void kernel_launch(void* const* d_in, const int* in_sizes, int n_in,
                              void* d_out, int out_size, void* d_ws, size_t ws_size,
                              hipStream_t stream) {
    const float* x  = (const float*)d_in[0];
    const float* Wq = (const float*)d_in[1];
    const float* bq = (const float*)d_in[2];
    const float* Wk = (const float*)d_in[3];
    const float* bk = (const float*)d_in[4];
    const float* Wv = (const float*)d_in[5];
    const float* bv = (const float*)d_in[6];
    const float* Wo = (const float*)d_in[7];
    const float* bo = (const float*)d_in[8];
    float* out = (float*)d_out;

    char* ws = (char*)d_ws;
    unsigned short* x_bf  = (unsigned short*)(ws);                      // 16 MB
    unsigned short* wq_bf = (unsigned short*)(ws + 16777216);           //  2 MB
    unsigned short* wk_bf = (unsigned short*)(ws + 18874368);           //  2 MB
    unsigned short* wv_bf = (unsigned short*)(ws + 20971520);           //  2 MB
    unsigned short* q_bf  = (unsigned short*)(ws + 23068672);           // 16 MB (pre-scaled Q)
    unsigned short* k_bf  = (unsigned short*)(ws + 39845888);           // 16 MB
    unsigned short* vt_bf = (unsigned short*)(ws + 56623104);           // 16 MB (V^T, granule-perm)
    float*          accp  = (float*)(ws + 73400320);                    // 16 KB

    // 144 KB dynamic LDS for the 3-buffer qkv pipeline
    hipFuncSetAttribute((const void*)qkv_gemm,
                        hipFuncAttributeMaxDynamicSharedMemorySize, 147456);

    conv_all<<<dim3(8192 + 3072), dim3(256), 0, stream>>>(
        x, Wq, Wk, Wv, x_bf, wq_bf, wk_bf, wv_bf, accp);

    qkv_gemm<<<dim3(768), dim3(512), 147456, stream>>>(
        x_bf, wq_bf, wk_bf, wv_bf, bq, bk, bv, q_bf, k_bf, vt_bf);

    attn_mfma<<<dim3(1024), dim3(128), 0, stream>>>(q_bf, k_bf, vt_bf, accp);

    out_proj<<<dim3(256), dim3(256), 0, stream>>>(accp, Wo, bo, out);
}